// Round 9
// baseline (246.865 us; speedup 1.0000x reference)
//
#include <hip/hip_runtime.h>

typedef __attribute__((ext_vector_type(8))) short short8;
typedef __attribute__((ext_vector_type(4))) short s16x4;
typedef __attribute__((ext_vector_type(4))) float f32x4;
typedef unsigned short u16t;
typedef unsigned int u32t;

#define MFMA16(a,b,c) __builtin_amdgcn_mfma_f32_16x16x32_bf16((a),(b),(c),0,0,0)

__device__ __forceinline__ f32x4 mfma16x16(s16x4 a, s16x4 b, f32x4 c) {
#if __has_builtin(__builtin_amdgcn_mfma_f32_16x16x16bf16_1k)
  return __builtin_amdgcn_mfma_f32_16x16x16bf16_1k(a, b, c, 0, 0, 0);
#else
  __asm__("v_mfma_f32_16x16x16_bf16 %0, %1, %2, %0" : "+v"(c) : "v"(a), "v"(b));
  return c;
#endif
}

constexpr int Bc = 2, Nc = 2048, Dc = 1024, NHc = 16, HDc = 64;
constexpr int EStride = Nc + 80;   // E rows per head incl. zero pad

__device__ __forceinline__ u16t f2bf(float f) {   // RTN (cold paths)
  union { float f; u32t u; } v; v.f = f;
  u32t r = v.u + 0x7FFFu + ((v.u >> 16) & 1u);
  return (u16t)(r >> 16);
}
// pack two floats -> bf16x2; HW packed cvt when available
#if __has_builtin(__builtin_amdgcn_cvt_pk_bf16_f32)
__device__ __forceinline__ u32t pk2(float a, float b) {
  auto r = __builtin_amdgcn_cvt_pk_bf16_f32(a, b);
  return __builtin_bit_cast(u32t, r);
}
#else
__device__ __forceinline__ u32t pk2(float a, float b) {
  u32t ua = __builtin_bit_cast(u32t, a);
  u32t ub = __builtin_bit_cast(u32t, b);
  return ((ua + 0x8000u) >> 16) | ((ub + 0x8000u) & 0xFFFF0000u);
}
#endif
__device__ __forceinline__ s16x4 pk4(float a, float b, float c, float d) {
  union { u32t u[2]; s16x4 s; } r;
  r.u[0] = pk2(a, b); r.u[1] = pk2(c, d);
  return r.s;
}

// async global->LDS, 16B per lane
__device__ __forceinline__ void gld16(const u16t* g, u16t* l) {
  __builtin_amdgcn_global_load_lds(
      (const __attribute__((address_space(1))) unsigned int*)(g),
      (__attribute__((address_space(3))) unsigned int*)(l), 16, 0, 0);
}

// ---------------- fused conversion: x, 4 weights, E remap + zero pad ----------------
__device__ __forceinline__ void cvt4(const float* s, u16t* d) {
  f32x4 v = *(const f32x4*)s;
  u32t* dp = (u32t*)d;
  dp[0] = pk2(v[0], v[1]); dp[1] = pk2(v[2], v[3]);
}

__global__ __launch_bounds__(256) void cvt_all(
    const float* __restrict__ x, const float* __restrict__ wq,
    const float* __restrict__ wk, const float* __restrict__ wv,
    const float* __restrict__ wp, const float* __restrict__ rel,
    u16t* __restrict__ xb, u16t* __restrict__ wqb, u16t* __restrict__ wkb,
    u16t* __restrict__ wvb, u16t* __restrict__ wpb, u16t* __restrict__ Eb) {
  int i = blockIdx.x * 256 + threadIdx.x;
  if (i < 1048576) {                        // x
    cvt4(x + (size_t)i * 4, xb + (size_t)i * 4);
  } else if (i < 2097152) {                 // weights
    int r = i - 1048576;
    int w = r >> 18;
    int k = (r & 262143) * 4;
    const float* s = (w == 0) ? wq : (w == 1) ? wk : (w == 2) ? wv : wp;
    u16t* d = (w == 0) ? wqb : (w == 1) ? wkb : (w == 2) ? wvb : wpb;
    cvt4(s + k, d + k);
  } else if (i < 2621440) {                 // E remap to [h][m][hd]
    int r = i - 2097152;
    int flat = r * 4;
    int h = flat >> 17;
    int rem = flat & 131071;
    int m = rem >> 6, d = rem & 63;
    cvt4(rel + (size_t)m * Dc + h * HDc + d,
         Eb + ((size_t)h * EStride + m) * HDc + d);
  } else {                                  // zero pad rows [Nc, Nc+80)
    int r = i - 2621440;
    int flat = r * 4;
    int h = flat / 5120;
    int rem = flat - h * 5120;
    int pr = rem >> 6, d = rem & 63;
    u32t* dp = (u32t*)(Eb + ((size_t)h * EStride + Nc + pr) * HDc + d);
    dp[0] = 0; dp[1] = 0;
  }
}

// ---------------- fused QKV GEMM: out = x @ W^T ----------------
// Q pre-scaled by 0.125*log2(e); V written directly transposed [bh][hd][n].
__global__ __launch_bounds__(256, 3) void gemm_qkv(const u16t* __restrict__ A,
    const u16t* __restrict__ Wq, const u16t* __restrict__ Wk,
    const u16t* __restrict__ Wv, u16t* __restrict__ Qb,
    u16t* __restrict__ Kb, u16t* __restrict__ Vt) {
  __shared__ u16t lA[128 * 32];   // unpadded: required by global_load_lds
  __shared__ u16t lB[128 * 32];
  const int y = blockIdx.y, which = y >> 3;
  const u16t* W = (which == 0) ? Wq : (which == 1) ? Wk : Wv;
  const float sc = (which == 0) ? 0.18033688011112042f : 1.0f;
  const int m0 = blockIdx.x * 128, n0 = (y & 7) * 128;
  const int t = threadIdx.x, wave = t >> 6, lane = t & 63;
  const int l15 = lane & 15, q4 = lane >> 4, wm = wave & 1, wn = wave >> 1;
  const int srow = wave * 16 + (lane >> 2);
  const int scol = (lane & 3) * 8;

  f32x4 acc[4][4];
  for (int i = 0; i < 4; i++)
    for (int j = 0; j < 4; j++)
      for (int r = 0; r < 4; r++) acc[i][j][r] = 0.f;

  for (int k0 = 0; k0 < Dc; k0 += 32) {
    __syncthreads();
    for (int r = 0; r < 2; r++) {
      int row = srow + r * 64;
      gld16(A + (size_t)(m0 + row) * Dc + k0 + scol, lA + wave * 512 + r * 2048);
      gld16(W + (size_t)(n0 + row) * Dc + k0 + scol, lB + wave * 512 + r * 2048);
    }
    __syncthreads();
    short8 af[4], bf[4];
    for (int i = 0; i < 4; i++) {
      af[i] = *(const short8*)(&lA[(wm * 64 + i * 16 + l15) * 32 + q4 * 8]);
      bf[i] = *(const short8*)(&lB[(wn * 64 + i * 16 + l15) * 32 + q4 * 8]);
    }
    for (int mi = 0; mi < 4; mi++)
      for (int ni = 0; ni < 4; ni++)
        acc[mi][ni] = MFMA16(af[mi], bf[ni], acc[mi][ni]);
  }

  if (which < 2) {
    for (int mi = 0; mi < 4; mi++)
      for (int ni = 0; ni < 4; ni++)
        for (int rg = 0; rg < 4; rg++) {
          int gm = m0 + wm * 64 + mi * 16 + q4 * 4 + rg;
          int gn = n0 + wn * 64 + ni * 16 + l15;
          int b = gm >> 11, n = gm & 2047, h = gn >> 6, hd = gn & 63;
          u16t* outb = (which == 0) ? Qb : Kb;
          outb[(((size_t)(b * NHc + h) * Nc + n) * HDc) + hd] =
              f2bf(acc[mi][ni][rg] * sc);
        }
  } else {
    // V: write transposed. rows of acc (rg) are consecutive n -> b64 stores.
    for (int mi = 0; mi < 4; mi++)
      for (int ni = 0; ni < 4; ni++) {
        int gm = m0 + wm * 64 + mi * 16 + q4 * 4;       // n base (rg=0)
        int gn = n0 + wn * 64 + ni * 16 + l15;
        int b = gm >> 11, n = gm & 2047, h = gn >> 6, hd = gn & 63;
        s16x4 pkv = pk4(acc[mi][ni][0], acc[mi][ni][1],
                        acc[mi][ni][2], acc[mi][ni][3]);
        *(s16x4*)(&Vt[((size_t)(b * NHc + h) * HDc + hd) * Nc + n]) = pkv;
      }
  }
}

// ---------------- output projection GEMM: out = AO @ Wp^T + bp (fp32) ----------------
// 64x128 tiles -> 512 blocks (2/CU) for latency hiding.
__global__ __launch_bounds__(256, 2) void gemm_proj(const u16t* __restrict__ A,
    const u16t* __restrict__ W, float* __restrict__ outf,
    const float* __restrict__ bias) {
  __shared__ u16t lA[64 * 32];
  __shared__ u16t lB[128 * 32];
  const int m0 = blockIdx.x * 64, n0 = blockIdx.y * 128;
  const int t = threadIdx.x, wave = t >> 6, lane = t & 63;
  const int l15 = lane & 15, q4 = lane >> 4, wm = wave & 1, wn = wave >> 1;
  const int srow = wave * 16 + (lane >> 2);
  const int scol = (lane & 3) * 8;

  f32x4 acc[2][4];
  for (int i = 0; i < 2; i++)
    for (int j = 0; j < 4; j++)
      for (int r = 0; r < 4; r++) acc[i][j][r] = 0.f;

  for (int k0 = 0; k0 < Dc; k0 += 32) {
    __syncthreads();
    gld16(A + (size_t)(m0 + srow) * Dc + k0 + scol, lA + wave * 512);
    for (int r = 0; r < 2; r++) {
      int row = srow + r * 64;
      gld16(W + (size_t)(n0 + row) * Dc + k0 + scol, lB + wave * 512 + r * 2048);
    }
    __syncthreads();
    short8 af[2], bf[4];
    for (int i = 0; i < 2; i++)
      af[i] = *(const short8*)(&lA[(wm * 32 + i * 16 + l15) * 32 + q4 * 8]);
    for (int i = 0; i < 4; i++)
      bf[i] = *(const short8*)(&lB[(wn * 64 + i * 16 + l15) * 32 + q4 * 8]);
    for (int mi = 0; mi < 2; mi++)
      for (int ni = 0; ni < 4; ni++)
        acc[mi][ni] = MFMA16(af[mi], bf[ni], acc[mi][ni]);
  }

  for (int mi = 0; mi < 2; mi++)
    for (int ni = 0; ni < 4; ni++)
      for (int rg = 0; rg < 4; rg++) {
        int gm = m0 + wm * 32 + mi * 16 + q4 * 4 + rg;
        int gn = n0 + wn * 64 + ni * 16 + l15;
        outf[(size_t)gm * Dc + gn] = acc[mi][ni][rg] + bias[gn];
      }
}

// ---------------- fused causal attention (transposed, E from global, K/V dbuf) ----------------
// S^T = MFMA(K,Q) from LDS; Pe^T = MFMA(E,Qs) with E A-frags loaded DIRECTLY
// from global (padded Eb; L2-resident). K/V double-buffered in LDS -> ONE
// barrier per step: writes for step j+1 target the idle buffer, which was
// last read in step j-1 (reads complete before this step's barrier).
__global__ __launch_bounds__(256, 2) void attn(const u16t* __restrict__ Qb,
                                               const u16t* __restrict__ Kb,
                                               const u16t* __restrict__ Vt,
                                               const u16t* __restrict__ Eb,
                                               u16t* __restrict__ AO) {
  __shared__ u16t lK[2][64 * 72];
  __shared__ u16t lV[2][64 * 72];
  __shared__ float Ps[4][16 * 84];   // wave-private fp32 srel scratch

  const int xbk = blockIdx.x;        // 0..15
  const int h = blockIdx.y, b = blockIdx.z;
  const u16t* Qh = Qb + (size_t)(b * NHc + h) * Nc * HDc;
  const u16t* Kh = Kb + (size_t)(b * NHc + h) * Nc * HDc;
  const u16t* Vh = Vt + (size_t)(b * NHc + h) * HDc * Nc;
  const u16t* Eh = Eb + (size_t)h * EStride * HDc;

  const int t = threadIdx.x, wave = t >> 6, lane = t & 63, l15 = lane & 15, q4 = lane >> 4;
  const int tbase = (3 - wave) * 16;
  const int Tm = wave * 16 + l15;    // causal threshold for the peeled step
  float* Pw = Ps[wave];

  const int sr = t >> 3, sc8 = (t & 7) * 8;
  const int sr2 = sr + 32;
  // E row pointer for this lane's A-frag rows (row = ebase + tbase + pt*16 + l15)
  const u16t* Ew = Eh + (size_t)(tbase + l15) * HDc + q4 * 8;

  for (int ph = 0; ph < 2; ph++) {
    const int qi = ph ? xbk : (31 - xbk);
    const int r0 = qi * 64;
    const int rw = r0 + wave * 16;

    short8 qf[2], qsf[2];
    {
      int r = rw + l15;
      int rs = r - 1; if (rs < 0) rs = 0;
      for (int kh = 0; kh < 2; kh++) {
        qf[kh]  = *(const short8*)(Qh + (size_t)r * HDc + kh * 32 + q4 * 8);
        qsf[kh] = *(const short8*)(Qh + (size_t)rs * HDc + kh * 32 + q4 * 8);
      }
    }

    f32x4 accO[4];
    float l_p = 0.f;
    for (int dt = 0; dt < 4; dt++)
      for (int rg = 0; rg < 4; rg++) accO[dt][rg] = 0.f;

    // step body: E global loads, S MFMA, P MFMA, srel shift, exp2, PV MFMA
    auto body = [&](int j, int buf, bool last) {
      const u16t* lKb = lK[buf];
      const u16t* lVb = lV[buf];
      // ---- E A-frags direct from global ----
      const int eb = 64 * j - r0 + (Nc - 63);
      short8 efr[2][5];
      for (int kh = 0; kh < 2; kh++)
        for (int pt = 0; pt < 5; pt++)
          efr[kh][pt] = *(const short8*)(Ew + ((size_t)(eb + pt * 16)) * HDc + kh * 32);
      // ---- S^T = MFMA(K, Q): D[kv][qrow] ----
      f32x4 accS[4];
      for (int ct = 0; ct < 4; ct++)
        for (int rg = 0; rg < 4; rg++) accS[ct][rg] = 0.f;
      for (int kh = 0; kh < 2; kh++)
        for (int ct = 0; ct < 4; ct++) {
          short8 kfr = *(const short8*)(&lKb[(ct * 16 + l15) * 72 + kh * 32 + q4 * 8]);
          accS[ct] = MFMA16(kfr, qf[kh], accS[ct]);
        }
      // ---- Pe^T = MFMA(E, Qs): D[t][qrow] ----
      f32x4 accP[5];
      for (int pt = 0; pt < 5; pt++)
        for (int rg = 0; rg < 4; rg++) accP[pt][rg] = 0.f;
      for (int kh = 0; kh < 2; kh++)
        for (int pt = 0; pt < 5; pt++)
          accP[pt] = MFMA16(efr[kh][pt], qsf[kh], accP[pt]);
      // scratch write: Ps[u=l15][c = pt*16+q4*4+rg] (rg consecutive -> b128)
      for (int pt = 0; pt < 5; pt++)
        *(f32x4*)(&Pw[l15 * 84 + pt * 16 + q4 * 4]) = accP[pt];
      __asm__ volatile("s_waitcnt lgkmcnt(0)" ::: "memory");
      // srel(u=l15, v=ct*16+q4*4+rg) = Ps[l15][v + 15 - l15]
      const int rbase = l15 * 83 + q4 * 4 + 15;
      float pv[4][4];
      for (int ct = 0; ct < 4; ct++)
        for (int rg = 0; rg < 4; rg++) {
          float s = accS[ct][rg] + Pw[rbase + ct * 16 + rg];
          if (last && (ct * 16 + q4 * 4 + rg) > Tm) s = -1e30f;
          float p = exp2f(s);
          l_p += p;
          pv[ct][rg] = p;
        }
      __asm__ volatile("" ::: "memory");
      // ---- O^T += V^T P^T ----
      s16x4 bq[4];
      for (int ks = 0; ks < 4; ks++)
        bq[ks] = pk4(pv[ks][0], pv[ks][1], pv[ks][2], pv[ks][3]);
      for (int dt = 0; dt < 4; dt++)
        for (int ks = 0; ks < 4; ks++) {
          s16x4 vfr = *(const s16x4*)(&lVb[(dt * 16 + l15) * 72 + ks * 16 + q4 * 4]);
          accO[dt] = mfma16x16(vfr, bq[ks], accO[dt]);
        }
    };

    // ---- initial stage (tile j=0) into buffer 0 ----
    __syncthreads();   // protect previous phase's last reads of buffer 0
    {
      *(f32x4*)(&lK[0][sr * 72 + sc8])  = *(const f32x4*)(Kh + (size_t)sr * HDc + sc8);
      *(f32x4*)(&lK[0][sr2 * 72 + sc8]) = *(const f32x4*)(Kh + (size_t)sr2 * HDc + sc8);
      *(f32x4*)(&lV[0][sr * 72 + sc8])  = *(const f32x4*)(Vh + (size_t)sr * Nc + sc8);
      *(f32x4*)(&lV[0][sr2 * 72 + sc8]) = *(const f32x4*)(Vh + (size_t)sr2 * Nc + sc8);
    }

    // ---- main loop: one barrier per step; writes go to the idle buffer ----
    for (int j = 0; j < qi; j++) {
      __syncthreads();   // buffer[j&1] writes visible; buffer[(j+1)&1] free
      const int cn = j * 64 + 64;
      f32x4 pK0 = *(const f32x4*)(Kh + (size_t)(cn + sr) * HDc + sc8);
      f32x4 pK1 = *(const f32x4*)(Kh + (size_t)(cn + sr2) * HDc + sc8);
      f32x4 pV0 = *(const f32x4*)(Vh + (size_t)sr * Nc + cn + sc8);
      f32x4 pV1 = *(const f32x4*)(Vh + (size_t)sr2 * Nc + cn + sc8);

      body(j, j & 1, false);

      const int nb = (j + 1) & 1;
      *(f32x4*)(&lK[nb][sr * 72 + sc8])  = pK0;
      *(f32x4*)(&lK[nb][sr2 * 72 + sc8]) = pK1;
      *(f32x4*)(&lV[nb][sr * 72 + sc8])  = pV0;
      *(f32x4*)(&lV[nb][sr2 * 72 + sc8]) = pV1;
    }

    // ---- peeled final (masked) step ----
    __syncthreads();
    body(qi, qi & 1, true);

    // ---- epilogue: reduce l across q4 groups, b64 stores ----
    float l2 = l_p + __shfl_xor(l_p, 16);
    float lt = l2 + __shfl_xor(l2, 32);
    float inv = 1.f / lt;
    {
      int r = rw + l15;
      u16t* dst = AO + (size_t)(b * Nc + r) * Dc + h * HDc + q4 * 4;
      for (int dt = 0; dt < 4; dt++) {
        s16x4 o = pk4(accO[dt][0] * inv, accO[dt][1] * inv,
                      accO[dt][2] * inv, accO[dt][3] * inv);
        *(s16x4*)(dst + dt * 16) = o;
      }
    }
  }
}

// ---------------- host ----------------
extern "C" void kernel_launch(void* const* d_in, const int* in_sizes, int n_in,
                              void* d_out, int out_size, void* d_ws, size_t ws_size,
                              hipStream_t stream) {
  (void)in_sizes; (void)n_in; (void)out_size; (void)ws_size;
  const float* x   = (const float*)d_in[0];
  const float* Wq  = (const float*)d_in[1];
  const float* Wk  = (const float*)d_in[2];
  const float* Wv  = (const float*)d_in[3];
  const float* Wp  = (const float*)d_in[4];
  const float* bp  = (const float*)d_in[5];
  const float* rel = (const float*)d_in[6];
  float* out = (float*)d_out;

  char* ws = (char*)d_ws;
  u16t* xb  = (u16t*)(ws);
  u16t* wqb = (u16t*)(ws + 8388608);
  u16t* wkb = (u16t*)(ws + 10485760);
  u16t* wvb = (u16t*)(ws + 12582912);
  u16t* wpb = (u16t*)(ws + 14680064);
  u16t* Eb  = (u16t*)(ws + 16777216);   // 16*2128*64*2 = 4358144 B
  u16t* Qb  = (u16t*)(ws + 21233664);
  u16t* Kb  = (u16t*)(ws + 29622272);
  u16t* Vtb = (u16t*)(ws + 38010880);
  u16t* AOb = (u16t*)(ws + 46399488);

  cvt_all<<<10320, 256, 0, stream>>>(x, Wq, Wk, Wv, Wp, rel,
                                     xb, wqb, wkb, wvb, wpb, Eb);
  gemm_qkv<<<dim3(32, 24), 256, 0, stream>>>(xb, wqb, wkb, wvb, Qb, Kb, Vtb);
  attn<<<dim3(16, NHc, Bc), 256, 0, stream>>>(Qb, Kb, Vtb, Eb, AOb);
  gemm_proj<<<dim3(64, 8), 256, 0, stream>>>(AOb, wpb, out, bp);
}

// Round 10
// 235.892 us; speedup vs baseline: 1.0465x; 1.0465x over previous
//
#include <hip/hip_runtime.h>

typedef __attribute__((ext_vector_type(8))) short short8;
typedef __attribute__((ext_vector_type(4))) short s16x4;
typedef __attribute__((ext_vector_type(4))) float f32x4;
typedef unsigned short u16t;
typedef unsigned int u32t;

#define MFMA16(a,b,c) __builtin_amdgcn_mfma_f32_16x16x32_bf16((a),(b),(c),0,0,0)

__device__ __forceinline__ f32x4 mfma16x16(s16x4 a, s16x4 b, f32x4 c) {
#if __has_builtin(__builtin_amdgcn_mfma_f32_16x16x16bf16_1k)
  return __builtin_amdgcn_mfma_f32_16x16x16bf16_1k(a, b, c, 0, 0, 0);
#else
  __asm__("v_mfma_f32_16x16x16_bf16 %0, %1, %2, %0" : "+v"(c) : "v"(a), "v"(b));
  return c;
#endif
}

constexpr int Bc = 2, Nc = 2048, Dc = 1024, NHc = 16, HDc = 64;
constexpr int EStride = Nc + 80;   // E rows per head incl. zero pad

__device__ __forceinline__ u16t f2bf(float f) {   // RTN (cold paths)
  union { float f; u32t u; } v; v.f = f;
  u32t r = v.u + 0x7FFFu + ((v.u >> 16) & 1u);
  return (u16t)(r >> 16);
}
// pack two floats -> bf16x2; HW packed cvt when available
#if __has_builtin(__builtin_amdgcn_cvt_pk_bf16_f32)
__device__ __forceinline__ u32t pk2(float a, float b) {
  auto r = __builtin_amdgcn_cvt_pk_bf16_f32(a, b);
  return __builtin_bit_cast(u32t, r);
}
#else
__device__ __forceinline__ u32t pk2(float a, float b) {
  u32t ua = __builtin_bit_cast(u32t, a);
  u32t ub = __builtin_bit_cast(u32t, b);
  return ((ua + 0x8000u) >> 16) | ((ub + 0x8000u) & 0xFFFF0000u);
}
#endif
__device__ __forceinline__ s16x4 pk4(float a, float b, float c, float d) {
  union { u32t u[2]; s16x4 s; } r;
  r.u[0] = pk2(a, b); r.u[1] = pk2(c, d);
  return r.s;
}

// async global->LDS, 16B per lane
__device__ __forceinline__ void gld16(const u16t* g, u16t* l) {
  __builtin_amdgcn_global_load_lds(
      (const __attribute__((address_space(1))) unsigned int*)(g),
      (__attribute__((address_space(3))) unsigned int*)(l), 16, 0, 0);
}

// ---------------- fused conversion: x, 4 weights, E remap + zero pad ----------------
__device__ __forceinline__ void cvt4(const float* s, u16t* d) {
  f32x4 v = *(const f32x4*)s;
  u32t* dp = (u32t*)d;
  dp[0] = pk2(v[0], v[1]); dp[1] = pk2(v[2], v[3]);
}

__global__ __launch_bounds__(256) void cvt_all(
    const float* __restrict__ x, const float* __restrict__ wq,
    const float* __restrict__ wk, const float* __restrict__ wv,
    const float* __restrict__ wp, const float* __restrict__ rel,
    u16t* __restrict__ xb, u16t* __restrict__ wqb, u16t* __restrict__ wkb,
    u16t* __restrict__ wvb, u16t* __restrict__ wpb, u16t* __restrict__ Eb) {
  int i = blockIdx.x * 256 + threadIdx.x;
  if (i < 1048576) {                        // x
    cvt4(x + (size_t)i * 4, xb + (size_t)i * 4);
  } else if (i < 2097152) {                 // weights
    int r = i - 1048576;
    int w = r >> 18;
    int k = (r & 262143) * 4;
    const float* s = (w == 0) ? wq : (w == 1) ? wk : (w == 2) ? wv : wp;
    u16t* d = (w == 0) ? wqb : (w == 1) ? wkb : (w == 2) ? wvb : wpb;
    cvt4(s + k, d + k);
  } else if (i < 2621440) {                 // E remap to [h][m][hd]
    int r = i - 2097152;
    int flat = r * 4;
    int h = flat >> 17;
    int rem = flat & 131071;
    int m = rem >> 6, d = rem & 63;
    cvt4(rel + (size_t)m * Dc + h * HDc + d,
         Eb + ((size_t)h * EStride + m) * HDc + d);
  } else {                                  // zero pad rows [Nc, Nc+80)
    int r = i - 2621440;
    int flat = r * 4;
    int h = flat / 5120;
    int rem = flat - h * 5120;
    int pr = rem >> 6, d = rem & 63;
    u32t* dp = (u32t*)(Eb + ((size_t)h * EStride + Nc + pr) * HDc + d);
    dp[0] = 0; dp[1] = 0;
  }
}

// ---------------- fused QKV GEMM: out = x @ W^T ----------------
// Q pre-scaled by 0.125*log2(e); V written directly transposed [bh][hd][n].
__global__ __launch_bounds__(256, 3) void gemm_qkv(const u16t* __restrict__ A,
    const u16t* __restrict__ Wq, const u16t* __restrict__ Wk,
    const u16t* __restrict__ Wv, u16t* __restrict__ Qb,
    u16t* __restrict__ Kb, u16t* __restrict__ Vt) {
  __shared__ u16t lA[128 * 32];   // unpadded: required by global_load_lds
  __shared__ u16t lB[128 * 32];
  const int y = blockIdx.y, which = y >> 3;
  const u16t* W = (which == 0) ? Wq : (which == 1) ? Wk : Wv;
  const float sc = (which == 0) ? 0.18033688011112042f : 1.0f;
  const int m0 = blockIdx.x * 128, n0 = (y & 7) * 128;
  const int t = threadIdx.x, wave = t >> 6, lane = t & 63;
  const int l15 = lane & 15, q4 = lane >> 4, wm = wave & 1, wn = wave >> 1;
  const int srow = wave * 16 + (lane >> 2);
  const int scol = (lane & 3) * 8;

  f32x4 acc[4][4];
  for (int i = 0; i < 4; i++)
    for (int j = 0; j < 4; j++)
      for (int r = 0; r < 4; r++) acc[i][j][r] = 0.f;

  for (int k0 = 0; k0 < Dc; k0 += 32) {
    __syncthreads();
    for (int r = 0; r < 2; r++) {
      int row = srow + r * 64;
      gld16(A + (size_t)(m0 + row) * Dc + k0 + scol, lA + wave * 512 + r * 2048);
      gld16(W + (size_t)(n0 + row) * Dc + k0 + scol, lB + wave * 512 + r * 2048);
    }
    __syncthreads();
    short8 af[4], bf[4];
    for (int i = 0; i < 4; i++) {
      af[i] = *(const short8*)(&lA[(wm * 64 + i * 16 + l15) * 32 + q4 * 8]);
      bf[i] = *(const short8*)(&lB[(wn * 64 + i * 16 + l15) * 32 + q4 * 8]);
    }
    for (int mi = 0; mi < 4; mi++)
      for (int ni = 0; ni < 4; ni++)
        acc[mi][ni] = MFMA16(af[mi], bf[ni], acc[mi][ni]);
  }

  if (which < 2) {
    for (int mi = 0; mi < 4; mi++)
      for (int ni = 0; ni < 4; ni++)
        for (int rg = 0; rg < 4; rg++) {
          int gm = m0 + wm * 64 + mi * 16 + q4 * 4 + rg;
          int gn = n0 + wn * 64 + ni * 16 + l15;
          int b = gm >> 11, n = gm & 2047, h = gn >> 6, hd = gn & 63;
          u16t* outb = (which == 0) ? Qb : Kb;
          outb[(((size_t)(b * NHc + h) * Nc + n) * HDc) + hd] =
              f2bf(acc[mi][ni][rg] * sc);
        }
  } else {
    // V: write transposed. rows of acc (rg) are consecutive n -> b64 stores.
    for (int mi = 0; mi < 4; mi++)
      for (int ni = 0; ni < 4; ni++) {
        int gm = m0 + wm * 64 + mi * 16 + q4 * 4;       // n base (rg=0)
        int gn = n0 + wn * 64 + ni * 16 + l15;
        int b = gm >> 11, n = gm & 2047, h = gn >> 6, hd = gn & 63;
        s16x4 pkv = pk4(acc[mi][ni][0], acc[mi][ni][1],
                        acc[mi][ni][2], acc[mi][ni][3]);
        *(s16x4*)(&Vt[((size_t)(b * NHc + h) * HDc + hd) * Nc + n]) = pkv;
      }
  }
}

// ---------------- output projection GEMM: out = AO @ Wp^T + bp (fp32) ----------------
__global__ __launch_bounds__(256, 2) void gemm_proj(const u16t* __restrict__ A,
    const u16t* __restrict__ W, float* __restrict__ outf,
    const float* __restrict__ bias) {
  __shared__ u16t lA[64 * 32];
  __shared__ u16t lB[128 * 32];
  const int m0 = blockIdx.x * 64, n0 = blockIdx.y * 128;
  const int t = threadIdx.x, wave = t >> 6, lane = t & 63;
  const int l15 = lane & 15, q4 = lane >> 4, wm = wave & 1, wn = wave >> 1;
  const int srow = wave * 16 + (lane >> 2);
  const int scol = (lane & 3) * 8;

  f32x4 acc[2][4];
  for (int i = 0; i < 2; i++)
    for (int j = 0; j < 4; j++)
      for (int r = 0; r < 4; r++) acc[i][j][r] = 0.f;

  for (int k0 = 0; k0 < Dc; k0 += 32) {
    __syncthreads();
    gld16(A + (size_t)(m0 + srow) * Dc + k0 + scol, lA + wave * 512);
    for (int r = 0; r < 2; r++) {
      int row = srow + r * 64;
      gld16(W + (size_t)(n0 + row) * Dc + k0 + scol, lB + wave * 512 + r * 2048);
    }
    __syncthreads();
    short8 af[2], bf[4];
    for (int i = 0; i < 2; i++)
      af[i] = *(const short8*)(&lA[(wm * 32 + i * 16 + l15) * 32 + q4 * 8]);
    for (int i = 0; i < 4; i++)
      bf[i] = *(const short8*)(&lB[(wn * 64 + i * 16 + l15) * 32 + q4 * 8]);
    for (int mi = 0; mi < 2; mi++)
      for (int ni = 0; ni < 4; ni++)
        acc[mi][ni] = MFMA16(af[mi], bf[ni], acc[mi][ni]);
  }

  for (int mi = 0; mi < 2; mi++)
    for (int ni = 0; ni < 4; ni++)
      for (int rg = 0; rg < 4; rg++) {
        int gm = m0 + wm * 32 + mi * 16 + q4 * 4 + rg;
        int gn = n0 + wn * 64 + ni * 16 + l15;
        outf[(size_t)gm * Dc + gn] = acc[mi][ni][rg] + bias[gn];
      }
}

// ---------------- fused causal attention ----------------
// Transposed compute; K/V double-buffered in LDS (one barrier/step); E
// A-frags REGISTER-prefetched one full step ahead from global (R9 lesson:
// demand E-loads expose L2 latency on the critical path; prefetched they
// are free). Main loop unrolled x2 so eA/eB <-> buf0/buf1 parities are
// compile-time constant (no reg copies, no dynamic local indexing).
__global__ __launch_bounds__(256, 2) void attn(const u16t* __restrict__ Qb,
                                               const u16t* __restrict__ Kb,
                                               const u16t* __restrict__ Vt,
                                               const u16t* __restrict__ Eb,
                                               u16t* __restrict__ AO) {
  __shared__ u16t lK[2][64 * 72];
  __shared__ u16t lV[2][64 * 72];
  __shared__ float Ps[4][16 * 84];   // wave-private fp32 srel scratch

  const int xbk = blockIdx.x;        // 0..15
  const int h = blockIdx.y, b = blockIdx.z;
  const u16t* Qh = Qb + (size_t)(b * NHc + h) * Nc * HDc;
  const u16t* Kh = Kb + (size_t)(b * NHc + h) * Nc * HDc;
  const u16t* Vh = Vt + (size_t)(b * NHc + h) * HDc * Nc;
  const u16t* Eh = Eb + (size_t)h * EStride * HDc;

  const int t = threadIdx.x, wave = t >> 6, lane = t & 63, l15 = lane & 15, q4 = lane >> 4;
  const int tbase = (3 - wave) * 16;
  const int Tm = wave * 16 + l15;    // causal threshold for the peeled step
  float* Pw = Ps[wave];

  const int sr = t >> 3, sc8 = (t & 7) * 8;
  const int sr2 = sr + 32;
  // E row pointer for this lane's A-frag rows (row = eb + tbase + pt*16 + l15)
  const u16t* Ew = Eh + (size_t)(tbase + l15) * HDc + q4 * 8;

  for (int ph = 0; ph < 2; ph++) {
    const int qi = ph ? xbk : (31 - xbk);
    const int r0 = qi * 64;
    const int rw = r0 + wave * 16;

    short8 qf[2], qsf[2];
    {
      int r = rw + l15;
      int rs = r - 1; if (rs < 0) rs = 0;
      for (int kh = 0; kh < 2; kh++) {
        qf[kh]  = *(const short8*)(Qh + (size_t)r * HDc + kh * 32 + q4 * 8);
        qsf[kh] = *(const short8*)(Qh + (size_t)rs * HDc + kh * 32 + q4 * 8);
      }
    }

    f32x4 accO[4];
    float l_p = 0.f;
    for (int dt = 0; dt < 4; dt++)
      for (int rg = 0; rg < 4; rg++) accO[dt][rg] = 0.f;

    // register E prefetch for step j (10 b128 global loads, lane-mapped A-frags)
    auto loadE = [&](int j, short8 efr[2][5]) {
      const int eb = 64 * j - r0 + (Nc - 63);   // rows in [1, Nc+16] (padded)
      for (int kh = 0; kh < 2; kh++)
        for (int pt = 0; pt < 5; pt++)
          efr[kh][pt] =
              *(const short8*)(Ew + (size_t)(eb + pt * 16) * HDc + kh * 32);
    };

    // step body: S MFMA, P MFMA (E regs), srel shift, exp2, PV MFMA
    auto body = [&](int buf, const short8 efr[2][5], bool last) {
      const u16t* lKb = lK[buf];
      const u16t* lVb = lV[buf];
      f32x4 accS[4];
      for (int ct = 0; ct < 4; ct++)
        for (int rg = 0; rg < 4; rg++) accS[ct][rg] = 0.f;
      for (int kh = 0; kh < 2; kh++)
        for (int ct = 0; ct < 4; ct++) {
          short8 kfr = *(const short8*)(&lKb[(ct * 16 + l15) * 72 + kh * 32 + q4 * 8]);
          accS[ct] = MFMA16(kfr, qf[kh], accS[ct]);
        }
      f32x4 accP[5];
      for (int pt = 0; pt < 5; pt++)
        for (int rg = 0; rg < 4; rg++) accP[pt][rg] = 0.f;
      for (int kh = 0; kh < 2; kh++)
        for (int pt = 0; pt < 5; pt++)
          accP[pt] = MFMA16(efr[kh][pt], qsf[kh], accP[pt]);
      // scratch write: Ps[u=l15][c = pt*16+q4*4+rg] (rg consecutive -> b128)
      for (int pt = 0; pt < 5; pt++)
        *(f32x4*)(&Pw[l15 * 84 + pt * 16 + q4 * 4]) = accP[pt];
      __asm__ volatile("s_waitcnt lgkmcnt(0)" ::: "memory");
      // srel(u=l15, v=ct*16+q4*4+rg) = Ps[l15][v + 15 - l15]
      const int rbase = l15 * 83 + q4 * 4 + 15;
      float pv[4][4];
      for (int ct = 0; ct < 4; ct++)
        for (int rg = 0; rg < 4; rg++) {
          float s = accS[ct][rg] + Pw[rbase + ct * 16 + rg];
          if (last && (ct * 16 + q4 * 4 + rg) > Tm) s = -1e30f;
          float p = exp2f(s);
          l_p += p;
          pv[ct][rg] = p;
        }
      __asm__ volatile("" ::: "memory");
      s16x4 bq[4];
      for (int ks = 0; ks < 4; ks++)
        bq[ks] = pk4(pv[ks][0], pv[ks][1], pv[ks][2], pv[ks][3]);
      for (int dt = 0; dt < 4; dt++)
        for (int ks = 0; ks < 4; ks++) {
          s16x4 vfr = *(const s16x4*)(&lVb[(dt * 16 + l15) * 72 + ks * 16 + q4 * 4]);
          accO[dt] = mfma16x16(vfr, bq[ks], accO[dt]);
        }
    };

    auto stageKV = [&](int cn, int buf) {   // register-prefetch + direct write
      f32x4 k0 = *(const f32x4*)(Kh + (size_t)(cn + sr) * HDc + sc8);
      f32x4 k1 = *(const f32x4*)(Kh + (size_t)(cn + sr2) * HDc + sc8);
      f32x4 v0 = *(const f32x4*)(Vh + (size_t)sr * Nc + cn + sc8);
      f32x4 v1 = *(const f32x4*)(Vh + (size_t)sr2 * Nc + cn + sc8);
      *(f32x4*)(&lK[buf][sr * 72 + sc8])  = k0;
      *(f32x4*)(&lK[buf][sr2 * 72 + sc8]) = k1;
      *(f32x4*)(&lV[buf][sr * 72 + sc8])  = v0;
      *(f32x4*)(&lV[buf][sr2 * 72 + sc8]) = v1;
    };

    short8 eA[2][5], eB[2][5];
    loadE(0, eA);
    __syncthreads();   // protect previous phase's last reads of the buffers
    stageKV(0, 0);

    int j = 0;
    for (; j + 1 < qi; j += 2) {
      __syncthreads();                       // buf0 visible, buf1 free
      {
        const int cn = j * 64 + 64;
        f32x4 k0 = *(const f32x4*)(Kh + (size_t)(cn + sr) * HDc + sc8);
        f32x4 k1 = *(const f32x4*)(Kh + (size_t)(cn + sr2) * HDc + sc8);
        f32x4 v0 = *(const f32x4*)(Vh + (size_t)sr * Nc + cn + sc8);
        f32x4 v1 = *(const f32x4*)(Vh + (size_t)sr2 * Nc + cn + sc8);
        loadE(j + 1, eB);
        body(0, eA, false);
        *(f32x4*)(&lK[1][sr * 72 + sc8])  = k0;
        *(f32x4*)(&lK[1][sr2 * 72 + sc8]) = k1;
        *(f32x4*)(&lV[1][sr * 72 + sc8])  = v0;
        *(f32x4*)(&lV[1][sr2 * 72 + sc8]) = v1;
      }
      __syncthreads();                       // buf1 visible, buf0 free
      {
        const int cn = j * 64 + 128;
        f32x4 k0 = *(const f32x4*)(Kh + (size_t)(cn + sr) * HDc + sc8);
        f32x4 k1 = *(const f32x4*)(Kh + (size_t)(cn + sr2) * HDc + sc8);
        f32x4 v0 = *(const f32x4*)(Vh + (size_t)sr * Nc + cn + sc8);
        f32x4 v1 = *(const f32x4*)(Vh + (size_t)sr2 * Nc + cn + sc8);
        loadE(j + 2, eA);
        body(1, eB, false);
        *(f32x4*)(&lK[0][sr * 72 + sc8])  = k0;
        *(f32x4*)(&lK[0][sr2 * 72 + sc8]) = k1;
        *(f32x4*)(&lV[0][sr * 72 + sc8])  = v0;
        *(f32x4*)(&lV[0][sr2 * 72 + sc8]) = v1;
      }
    }
    if (j < qi) {        // qi odd: one unmasked step (buf0/eA), then masked buf1/eB
      __syncthreads();
      {
        const int cn = j * 64 + 64;
        f32x4 k0 = *(const f32x4*)(Kh + (size_t)(cn + sr) * HDc + sc8);
        f32x4 k1 = *(const f32x4*)(Kh + (size_t)(cn + sr2) * HDc + sc8);
        f32x4 v0 = *(const f32x4*)(Vh + (size_t)sr * Nc + cn + sc8);
        f32x4 v1 = *(const f32x4*)(Vh + (size_t)sr2 * Nc + cn + sc8);
        loadE(j + 1, eB);
        body(0, eA, false);
        *(f32x4*)(&lK[1][sr * 72 + sc8])  = k0;
        *(f32x4*)(&lK[1][sr2 * 72 + sc8]) = k1;
        *(f32x4*)(&lV[1][sr * 72 + sc8])  = v0;
        *(f32x4*)(&lV[1][sr2 * 72 + sc8]) = v1;
      }
      __syncthreads();
      body(1, eB, true);
    } else {             // qi even: masked step on buf0/eA
      __syncthreads();
      body(0, eA, true);
    }

    // ---- epilogue: reduce l across q4 groups, b64 stores ----
    float l2 = l_p + __shfl_xor(l_p, 16);
    float lt = l2 + __shfl_xor(l2, 32);
    float inv = 1.f / lt;
    {
      int r = rw + l15;
      u16t* dst = AO + (size_t)(b * Nc + r) * Dc + h * HDc + q4 * 4;
      for (int dt = 0; dt < 4; dt++) {
        s16x4 o = pk4(accO[dt][0] * inv, accO[dt][1] * inv,
                      accO[dt][2] * inv, accO[dt][3] * inv);
        *(s16x4*)(dst + dt * 16) = o;
      }
    }
  }
}

// ---------------- host ----------------
extern "C" void kernel_launch(void* const* d_in, const int* in_sizes, int n_in,
                              void* d_out, int out_size, void* d_ws, size_t ws_size,
                              hipStream_t stream) {
  (void)in_sizes; (void)n_in; (void)out_size; (void)ws_size;
  const float* x   = (const float*)d_in[0];
  const float* Wq  = (const float*)d_in[1];
  const float* Wk  = (const float*)d_in[2];
  const float* Wv  = (const float*)d_in[3];
  const float* Wp  = (const float*)d_in[4];
  const float* bp  = (const float*)d_in[5];
  const float* rel = (const float*)d_in[6];
  float* out = (float*)d_out;

  char* ws = (char*)d_ws;
  u16t* xb  = (u16t*)(ws);
  u16t* wqb = (u16t*)(ws + 8388608);
  u16t* wkb = (u16t*)(ws + 10485760);
  u16t* wvb = (u16t*)(ws + 12582912);
  u16t* wpb = (u16t*)(ws + 14680064);
  u16t* Eb  = (u16t*)(ws + 16777216);   // 16*2128*64*2 = 4358144 B
  u16t* Qb  = (u16t*)(ws + 21233664);
  u16t* Kb  = (u16t*)(ws + 29622272);
  u16t* Vtb = (u16t*)(ws + 38010880);
  u16t* AOb = (u16t*)(ws + 46399488);

  cvt_all<<<10320, 256, 0, stream>>>(x, Wq, Wk, Wv, Wp, rel,
                                     xb, wqb, wkb, wvb, wpb, Eb);
  gemm_qkv<<<dim3(32, 24), 256, 0, stream>>>(xb, wqb, wkb, wvb, Qb, Kb, Vtb);
  attn<<<dim3(16, NHc, Bc), 256, 0, stream>>>(Qb, Kb, Vtb, Eb, AOb);
  gemm_proj<<<dim3(64, 8), 256, 0, stream>>>(AOb, wpb, out, bp);
}